// Round 2
// baseline (73.859 us; speedup 1.0000x reference)
//
#include <hip/hip_runtime.h>

typedef __bf16 bf16_t;
typedef bf16_t bf16x8 __attribute__((ext_vector_type(8)));
typedef float f32x4 __attribute__((ext_vector_type(4)));

#define Bsz 4096   // batch rows (M)
#define Csz 4096   // centers (N)
#define Dsz 1024   // data dim (K)
#define BM 256
#define BN 256
#define BK 64
#define NKT (Dsz/BK)        // 16 K-tiles
#define NPC 64              // partial column-groups: 16 n-tiles x 4 wc

// RNE f32 -> bf16 bits
__device__ inline unsigned short f2bf(float f){
  unsigned u = __float_as_uint(f);
  u += 0x7FFFu + ((u >> 16) & 1u);
  return (unsigned short)(u >> 16);
}

// ---------------- prep: x2/c2 (f32 exact) + bf16 conversion ----------------
__global__ __launch_bounds__(256) void prep_kernel(
    const float* __restrict__ x, const float* __restrict__ cen,
    unsigned short* __restrict__ xb, unsigned short* __restrict__ cb,
    float* __restrict__ x2, float* __restrict__ c2)
{
  int w = blockIdx.x * 4 + (threadIdx.x >> 6);   // global wave id, one row each
  int lane = threadIdx.x & 63;
  const float* src; unsigned short* dst; float* sq; int row;
  if (w < Bsz) { row = w;       src = x;   dst = xb; sq = x2; }
  else         { row = w - Bsz; src = cen; dst = cb; sq = c2; }

  const float4* s4 = (const float4*)(src + (size_t)row * Dsz);
  unsigned short* d = dst + (size_t)row * Dsz;
  float ss = 0.f;
  #pragma unroll
  for (int t = 0; t < 4; ++t){
    float4 v = s4[t * 64 + lane];
    ss += v.x*v.x + v.y*v.y + v.z*v.z + v.w*v.w;
    ushort4 u; u.x = f2bf(v.x); u.y = f2bf(v.y); u.z = f2bf(v.z); u.w = f2bf(v.w);
    *(ushort4*)(d + (size_t)(t * 64 + lane) * 4) = u;
  }
  #pragma unroll
  for (int off = 32; off >= 1; off >>= 1) ss += __shfl_xor(ss, off, 64);
  if (lane == 0) sq[row] = ss;
}

// ---------------- 256x256 8-phase fused GEMM + RBF epilogue ----------------
// 512 thr = 8 waves (2 wr x 4 wc). Per wave: 128x64 output = 8x4 frags 16x16.
// LDS: 2 bufs x (A 256x64 + B 256x64) bf16 = 128 KiB, XOR chunk-swizzled:
//   LDS[r][c16] = G[r][c16 ^ (r&7)]  (linear gload_lds dest, pre-swz source).
// Per K-tile: 4 phases (mh,nh quadrants). Stage schedule: B(t+1) at ph0,
// A(t+2) at ph3 (A-slots of buf[p] last read at ph2). Boundary: vmcnt(4).
__global__ __launch_bounds__(512, 2) void rbf_gemm_kernel(
    const unsigned short* __restrict__ xb, const unsigned short* __restrict__ cb,
    const float* __restrict__ x2, const float* __restrict__ c2,
    const float* __restrict__ beta, const float* __restrict__ W,
    float* __restrict__ partials)
{
  __shared__ __align__(16) unsigned short smem[65536];  // 128 KiB

  const int tid  = threadIdx.x;
  const int wid  = tid >> 6;
  const int lane = tid & 63;
  const int wr   = wid >> 2;        // 0..1
  const int wc   = wid & 3;         // 0..3
  const int l15  = lane & 15;
  const int lhi  = lane >> 4;
  const int bm   = blockIdx.x;      // 0..15
  const int bn   = blockIdx.y;      // 0..15

  const unsigned short* gA = xb + (size_t)(bm * BM) * Dsz;
  const unsigned short* gB = cb + (size_t)(bn * BN) * Dsz;

  // staging geometry: one gload_lds = 64 lanes x 16B; 512 thr cover 64 rows
  const int srow   = tid >> 3;                 // 0..63
  const int schunk = (tid & 7) ^ (srow & 7);   // pre-swizzled src 16B chunk

  // read-side swizzled chunk offsets (ushort units), kk = 0/1
  const int ach0 = ((lhi)     ^ (l15 & 7)) * 8;
  const int ach1 = ((4 + lhi) ^ (l15 & 7)) * 8;
  const int ldsA = wr * 8192;                  // A-half(wr) base (ushorts)
  const int ldsB = 16384 + (wc >> 1) * 8192;   // B-half(wc>>1) base
  const int bloc = (wc & 1) * 64;              // row offset within B-half

#define FENCE asm volatile("" ::: "memory")

#define STAGE_H(GP, LBASE, GROW0, KT) { \
    _Pragma("unroll") \
    for (int r_ = 0; r_ < 2; ++r_){ \
      const unsigned short* gsrc_ = (GP) + (size_t)((GROW0) + r_*64 + srow) * Dsz + (KT)*BK + schunk*8; \
      __builtin_amdgcn_global_load_lds( \
        (const __attribute__((address_space(1))) unsigned int*)gsrc_, \
        (__attribute__((address_space(3))) unsigned int*)&smem[(LBASE) + r_*4096 + wid*512], \
        16, 0, 0); \
    } }

#define STAGE_A2(P, KT) { STAGE_H(gA, (P)*32768 +     0,   0, KT) STAGE_H(gA, (P)*32768 +  8192, 128, KT) }
#define STAGE_B2(P, KT) { STAGE_H(gB, (P)*32768 + 16384,   0, KT) STAGE_H(gB, (P)*32768 + 24576, 128, KT) }

  f32x4 acc[8][4];
  #pragma unroll
  for (int mi = 0; mi < 8; ++mi)
    #pragma unroll
    for (int ni = 0; ni < 4; ++ni)
      acc[mi][ni] = (f32x4){0.f, 0.f, 0.f, 0.f};

  bf16x8 av[4][2], bv[2][2];

#define LD_AV(P, MH) { \
    _Pragma("unroll") \
    for (int mi_ = 0; mi_ < 4; ++mi_){ \
      const int ra_ = (MH)*64 + mi_*16 + l15; \
      av[mi_][0] = *(const bf16x8*)&smem[(P)*32768 + ldsA + ra_*64 + ach0]; \
      av[mi_][1] = *(const bf16x8*)&smem[(P)*32768 + ldsA + ra_*64 + ach1]; \
    } }

#define LD_BV(P, NH) { \
    _Pragma("unroll") \
    for (int ni_ = 0; ni_ < 2; ++ni_){ \
      const int rb_ = bloc + ((NH)*2 + ni_)*16 + l15; \
      bv[ni_][0] = *(const bf16x8*)&smem[(P)*32768 + ldsB + rb_*64 + ach0]; \
      bv[ni_][1] = *(const bf16x8*)&smem[(P)*32768 + ldsB + rb_*64 + ach1]; \
    } }

#define DO_MFMA(MH, NH) { \
    _Pragma("unroll") \
    for (int mi_ = 0; mi_ < 4; ++mi_) \
      _Pragma("unroll") \
      for (int ni_ = 0; ni_ < 2; ++ni_){ \
        acc[(MH)*4+mi_][(NH)*2+ni_] = __builtin_amdgcn_mfma_f32_16x16x32_bf16(av[mi_][0], bv[ni_][0], acc[(MH)*4+mi_][(NH)*2+ni_], 0,0,0); \
        acc[(MH)*4+mi_][(NH)*2+ni_] = __builtin_amdgcn_mfma_f32_16x16x32_bf16(av[mi_][1], bv[ni_][1], acc[(MH)*4+mi_][(NH)*2+ni_], 0,0,0); \
      } }

  // Phase: {ds_read subtile | stage} -> barrier -> setprio MFMA -> [vmcnt] -> barrier
#define DO_PHASE(P, MH, NH, STB, STA, T) { \
    if ((NH) == 0) LD_AV(P, MH) \
    LD_BV(P, NH) \
    if ((MH) == 0 && (NH) == 0 && (STB)) STAGE_B2(1-(P), (T)+1) \
    if ((MH) == 1 && (NH) == 1 && (STA)) STAGE_A2(P, (T)+2) \
    FENCE; __builtin_amdgcn_s_barrier(); FENCE; \
    __builtin_amdgcn_s_setprio(1); \
    DO_MFMA(MH, NH) \
    __builtin_amdgcn_s_setprio(0); \
    if ((MH) == 1 && (NH) == 1){ \
      if (STA) { asm volatile("s_waitcnt vmcnt(4)" ::: "memory"); } \
      else     { asm volatile("s_waitcnt vmcnt(0)" ::: "memory"); } \
    } \
    FENCE; __builtin_amdgcn_s_barrier(); FENCE; }

  // Prologue: A(0)->buf0, B(0)->buf0, A(1)->buf1; wait A(0),B(0); barrier.
  STAGE_A2(0, 0)
  STAGE_B2(0, 0)
  STAGE_A2(1, 1)
  asm volatile("s_waitcnt vmcnt(4)" ::: "memory");
  __builtin_amdgcn_s_barrier();
  FENCE;

  for (int tt = 0; tt < NKT; tt += 2){
    const int stb1 = (tt + 2 < NKT);   // stage B(tt+2) during tile tt+1
    const int sta0 = (tt + 2 < NKT);   // stage A(tt+2) during tile tt
    const int sta1 = (tt + 3 < NKT);   // stage A(tt+3) during tile tt+1
    // tile t = tt (p = 0)
    DO_PHASE(0, 0, 0, 1,    0,    tt)
    DO_PHASE(0, 0, 1, 0,    0,    tt)
    DO_PHASE(0, 1, 0, 0,    0,    tt)
    DO_PHASE(0, 1, 1, 0,    sta0, tt)
    // tile t = tt+1 (p = 1)
    DO_PHASE(1, 0, 0, stb1, 0,    tt+1)
    DO_PHASE(1, 0, 1, 0,    0,    tt+1)
    DO_PHASE(1, 1, 0, 0,    0,    tt+1)
    DO_PHASE(1, 1, 1, 0,    sta1, tt+1)
  }

  // ---- fused epilogue: d2 -> dist -> exp -> *W, then column-sum ----
  const int rowbase0 = bm * BM + wr * 128;
  f32x4 rs[8];
  #pragma unroll
  for (int mi = 0; mi < 8; ++mi) rs[mi] = (f32x4){0.f, 0.f, 0.f, 0.f};

  f32x4 x2r[8];
  #pragma unroll
  for (int mi = 0; mi < 8; ++mi)
    x2r[mi] = *(const f32x4*)&x2[rowbase0 + mi * 16 + lhi * 4];

  #pragma unroll
  for (int ni = 0; ni < 4; ++ni){
    const int col = bn * BN + wc * 64 + ni * 16 + l15;
    const float c2v = c2[col], bt = beta[col], wv = W[col];
    #pragma unroll
    for (int mi = 0; mi < 8; ++mi)
      #pragma unroll
      for (int j = 0; j < 4; ++j){
        float s    = acc[mi][ni][j];
        float d2   = x2r[mi][j] + c2v - 2.0f * s;
        float dist = sqrtf(fmaxf(d2, 0.0f));
        rs[mi][j] += wv * __expf(-bt * dist);   // exp(<=0) can't be inf
      }
  }

  // reduce over the 16 lanes holding different cols; write per-(bn,wc) partials
  const size_t pcbase = (size_t)(bn * 4 + wc) * Bsz;
  #pragma unroll
  for (int mi = 0; mi < 8; ++mi){
    #pragma unroll
    for (int j = 0; j < 4; ++j){
      float v = rs[mi][j];
      v += __shfl_xor(v, 1, 16);
      v += __shfl_xor(v, 2, 16);
      v += __shfl_xor(v, 4, 16);
      v += __shfl_xor(v, 8, 16);
      rs[mi][j] = v;
    }
    if (l15 == 0)
      *(f32x4*)&partials[pcbase + rowbase0 + mi * 16 + lhi * 4] = rs[mi];
  }
}

// ---------------- final reduction over column-groups ----------------
__global__ __launch_bounds__(256) void reduce_kernel(
    const float* __restrict__ partials, const float* __restrict__ bias,
    float* __restrict__ out)
{
  int b = blockIdx.x * 256 + threadIdx.x;
  float s = bias[0];
  #pragma unroll
  for (int t = 0; t < NPC; ++t) s += partials[(size_t)t * Bsz + b];
  out[b] = s;
}

// ---------------- naive f32 fallback (only if ws too small) ----------------
__global__ __launch_bounds__(256) void rbf_naive_kernel(
    const float* __restrict__ x, const float* __restrict__ cen,
    const float* __restrict__ beta, const float* __restrict__ W,
    const float* __restrict__ bias, float* __restrict__ out)
{
  __shared__ float4 xs4[Dsz / 4];
  __shared__ float red[256];
  int b = blockIdx.x;
  for (int i = threadIdx.x; i < Dsz / 4; i += 256)
    xs4[i] = ((const float4*)(x + (size_t)b * Dsz))[i];
  __syncthreads();
  float acc = 0.f;
  for (int j = threadIdx.x; j < Csz; j += 256){
    const float4* c4 = (const float4*)(cen + (size_t)j * Dsz);
    float d2 = 0.f;
    for (int k = 0; k < Dsz / 4; ++k){
      float4 cv = c4[k], xv = xs4[k];
      float a0 = xv.x - cv.x, a1 = xv.y - cv.y, a2 = xv.z - cv.z, a3 = xv.w - cv.w;
      d2 += a0*a0 + a1*a1 + a2*a2 + a3*a3;
    }
    acc += W[j] * expf(-beta[j] * sqrtf(fmaxf(d2, 0.f)));
  }
  red[threadIdx.x] = acc;
  __syncthreads();
  for (int s = 128; s >= 1; s >>= 1){
    if (threadIdx.x < s) red[threadIdx.x] += red[threadIdx.x + s];
    __syncthreads();
  }
  if (threadIdx.x == 0) out[b] = red[0] + bias[0];
}

extern "C" void kernel_launch(void* const* d_in, const int* in_sizes, int n_in,
                              void* d_out, int out_size, void* d_ws, size_t ws_size,
                              hipStream_t stream)
{
  const float* x    = (const float*)d_in[0];
  const float* cen  = (const float*)d_in[1];
  const float* beta = (const float*)d_in[2];
  const float* W    = (const float*)d_in[3];
  const float* bias = (const float*)d_in[4];
  float* out = (float*)d_out;

  const size_t off_xb = 0;
  const size_t off_cb = off_xb + (size_t)Bsz * Dsz * sizeof(unsigned short);
  const size_t off_x2 = off_cb + (size_t)Csz * Dsz * sizeof(unsigned short);
  const size_t off_c2 = off_x2 + (size_t)Bsz * sizeof(float);
  const size_t off_p  = off_c2 + (size_t)Csz * sizeof(float);
  const size_t need   = off_p  + (size_t)NPC * Bsz * sizeof(float);

  if (ws_size < need){
    rbf_naive_kernel<<<Bsz, 256, 0, stream>>>(x, cen, beta, W, bias, out);
    return;
  }

  char* ws = (char*)d_ws;
  unsigned short* xb = (unsigned short*)(ws + off_xb);
  unsigned short* cb = (unsigned short*)(ws + off_cb);
  float* x2 = (float*)(ws + off_x2);
  float* c2 = (float*)(ws + off_c2);
  float* pp = (float*)(ws + off_p);

  prep_kernel<<<(Bsz + Csz) / 4, 256, 0, stream>>>(x, cen, xb, cb, x2, c2);
  dim3 grid(Bsz / BM, Csz / BN);
  rbf_gemm_kernel<<<grid, 512, 0, stream>>>(xb, cb, x2, c2, beta, W, pp);
  reduce_kernel<<<Bsz / 256, 256, 0, stream>>>(pp, bias, out);
}

// Round 3
// 73.629 us; speedup vs baseline: 1.0031x; 1.0031x over previous
//
#include <hip/hip_runtime.h>

typedef __bf16 bf16_t;
typedef bf16_t bf16x8 __attribute__((ext_vector_type(8)));
typedef float f32x4 __attribute__((ext_vector_type(4)));

#define Bsz 4096   // batch rows (M)
#define Csz 4096   // centers (N)
#define Dsz 1024   // data dim (K)
#define BM 256
#define BN 256
#define BK 64
#define NKT (Dsz/BK)        // 16 K-tiles
#define NPC 64              // partial column-groups: 16 n-tiles x 4 wc

// RNE f32 -> bf16 bits
__device__ inline unsigned short f2bf(float f){
  unsigned u = __float_as_uint(f);
  u += 0x7FFFu + ((u >> 16) & 1u);
  return (unsigned short)(u >> 16);
}

// inline-asm LDS read: compiler cannot alias-analyze this against the
// global_load_lds prefetch queue, so it cannot insert vmcnt(0) drains.
__device__ __forceinline__ bf16x8 dsr128(unsigned byte_off){
  bf16x8 r;
  asm volatile("ds_read_b128 %0, %1" : "=v"(r) : "v"(byte_off));
  return r;
}

// ---------------- prep: x2/c2 (f32 exact) + bf16 conversion ----------------
__global__ __launch_bounds__(256) void prep_kernel(
    const float* __restrict__ x, const float* __restrict__ cen,
    unsigned short* __restrict__ xb, unsigned short* __restrict__ cb,
    float* __restrict__ x2, float* __restrict__ c2)
{
  int w = blockIdx.x * 4 + (threadIdx.x >> 6);   // global wave id, one row each
  int lane = threadIdx.x & 63;
  const float* src; unsigned short* dst; float* sq; int row;
  if (w < Bsz) { row = w;       src = x;   dst = xb; sq = x2; }
  else         { row = w - Bsz; src = cen; dst = cb; sq = c2; }

  const float4* s4 = (const float4*)(src + (size_t)row * Dsz);
  unsigned short* d = dst + (size_t)row * Dsz;
  float ss = 0.f;
  #pragma unroll
  for (int t = 0; t < 4; ++t){
    float4 v = s4[t * 64 + lane];
    ss += v.x*v.x + v.y*v.y + v.z*v.z + v.w*v.w;
    ushort4 u; u.x = f2bf(v.x); u.y = f2bf(v.y); u.z = f2bf(v.z); u.w = f2bf(v.w);
    *(ushort4*)(d + (size_t)(t * 64 + lane) * 4) = u;
  }
  #pragma unroll
  for (int off = 32; off >= 1; off >>= 1) ss += __shfl_xor(ss, off, 64);
  if (lane == 0) sq[row] = ss;
}

// ---------------- 256x256 8-phase fused GEMM + RBF epilogue ----------------
// 512 thr = 8 waves (2 wr x 4 wc). Per wave: 128x64 output = 8x4 frags 16x16.
// LDS: 2 bufs x (A 256x64 + B 256x64) bf16 = 128 KiB, XOR chunk-swizzled:
//   LDS[r][c16] = G[r][c16 ^ (r&7)]  (linear gload_lds dest, pre-swz source).
// Per K-tile: 4 phases (mh,nh). Stage slots (2 gload_lds/thread per phase):
//   ph0: A(t+1)h1   ph1: B(t+1)h0   ph2: B(t+1)h1   ph3: A(t+2)h0
// Boundary wait: vmcnt(2) (leaves A(t+2)h0 in flight). Never 0 mid-loop.
__global__ __launch_bounds__(512, 2) void rbf_gemm_kernel(
    const unsigned short* __restrict__ xb, const unsigned short* __restrict__ cb,
    const float* __restrict__ x2, const float* __restrict__ c2,
    const float* __restrict__ beta, const float* __restrict__ W,
    float* __restrict__ partials)
{
  __shared__ __align__(16) unsigned short smem[65536];  // 128 KiB

  const int tid  = threadIdx.x;
  const int wid  = tid >> 6;
  const int lane = tid & 63;
  const int wr   = wid >> 2;        // 0..1
  const int wc   = wid & 3;         // 0..3
  const int l15  = lane & 15;
  const int lhi  = lane >> 4;
  const int bm   = blockIdx.x;      // 0..15
  const int bn   = blockIdx.y;      // 0..15

  const unsigned short* gA = xb + (size_t)(bm * BM) * Dsz;
  const unsigned short* gB = cb + (size_t)(bn * BN) * Dsz;

  // staging geometry: one gload_lds = 64 lanes x 16B; 512 thr cover 64 rows
  const int srow   = tid >> 3;                 // 0..63
  const int schunk = (tid & 7) ^ (srow & 7);   // pre-swizzled src 16B chunk

  // read-side swizzled chunk offsets (ushort units), kk = 0/1
  const int ach0 = ((lhi)     ^ (l15 & 7)) * 8;
  const int ach1 = ((4 + lhi) ^ (l15 & 7)) * 8;
  const int ldsA = wr * 8192;                  // A-half(wr) base (ushorts)
  const int ldsB = 16384 + (wc >> 1) * 8192;   // B-half(wc>>1) base
  const int bloc = (wc & 1) * 64;              // row offset within B-half

  // 32-bit LDS byte offsets for inline-asm ds_read
  const unsigned lds_base =
      (unsigned)(uintptr_t)(__attribute__((address_space(3))) unsigned short*)smem;
  const unsigned aoff0 = lds_base + (unsigned)(ldsA + l15 * 64 + ach0) * 2u;
  const unsigned aoff1 = lds_base + (unsigned)(ldsA + l15 * 64 + ach1) * 2u;
  const unsigned boff0 = lds_base + (unsigned)(ldsB + (bloc + l15) * 64 + ach0) * 2u;
  const unsigned boff1 = lds_base + (unsigned)(ldsB + (bloc + l15) * 64 + ach1) * 2u;

#define STAGE_H(GP, LBASE, GROW0, KT) { \
    const unsigned short* gsrc_ = (GP) + (size_t)((GROW0) + srow) * Dsz + (KT)*BK + schunk*8; \
    __builtin_amdgcn_global_load_lds( \
      (const __attribute__((address_space(1))) unsigned int*)gsrc_, \
      (__attribute__((address_space(3))) unsigned int*)&smem[(LBASE) + wid*512], 16, 0, 0); \
    __builtin_amdgcn_global_load_lds( \
      (const __attribute__((address_space(1))) unsigned int*)(gsrc_ + (size_t)64 * Dsz), \
      (__attribute__((address_space(3))) unsigned int*)&smem[(LBASE) + 4096 + wid*512], 16, 0, 0); }

#define STAGE_AH(P, H, KT) STAGE_H(gA, (P)*32768 + (H)*8192,         (H)*128, KT)
#define STAGE_BH(P, H, KT) STAGE_H(gB, (P)*32768 + 16384 + (H)*8192, (H)*128, KT)

  f32x4 acc[8][4];
  #pragma unroll
  for (int mi = 0; mi < 8; ++mi)
    #pragma unroll
    for (int ni = 0; ni < 4; ++ni)
      acc[mi][ni] = (f32x4){0.f, 0.f, 0.f, 0.f};

  bf16x8 av[4][2], bv[2][2];

#define LD_AV(P, MH) { \
    _Pragma("unroll") \
    for (int mi_ = 0; mi_ < 4; ++mi_){ \
      av[mi_][0] = dsr128(aoff0 + (P)*65536u + (MH)*8192u + mi_*2048u); \
      av[mi_][1] = dsr128(aoff1 + (P)*65536u + (MH)*8192u + mi_*2048u); \
    } }

#define LD_BV(P, NH) { \
    _Pragma("unroll") \
    for (int ni_ = 0; ni_ < 2; ++ni_){ \
      bv[ni_][0] = dsr128(boff0 + (P)*65536u + (NH)*4096u + ni_*2048u); \
      bv[ni_][1] = dsr128(boff1 + (P)*65536u + (NH)*4096u + ni_*2048u); \
    } }

#define DO_MFMA(MH, NH) { \
    _Pragma("unroll") \
    for (int mi_ = 0; mi_ < 4; ++mi_) \
      _Pragma("unroll") \
      for (int ni_ = 0; ni_ < 2; ++ni_){ \
        acc[(MH)*4+mi_][(NH)*2+ni_] = __builtin_amdgcn_mfma_f32_16x16x32_bf16(av[mi_][0], bv[ni_][0], acc[(MH)*4+mi_][(NH)*2+ni_], 0,0,0); \
        acc[(MH)*4+mi_][(NH)*2+ni_] = __builtin_amdgcn_mfma_f32_16x16x32_bf16(av[mi_][1], bv[ni_][1], acc[(MH)*4+mi_][(NH)*2+ni_], 0,0,0); \
      } }

  // barrier -> lgkmcnt(0) -> sched_barrier (rule 18) -> setprio MFMA cluster
#define PH_MFMA(MH, NH) \
    __builtin_amdgcn_sched_barrier(0); \
    __builtin_amdgcn_s_barrier(); \
    asm volatile("s_waitcnt lgkmcnt(0)" ::: "memory"); \
    __builtin_amdgcn_sched_barrier(0); \
    __builtin_amdgcn_s_setprio(1); \
    DO_MFMA(MH, NH) \
    __builtin_amdgcn_s_setprio(0); \
    __builtin_amdgcn_sched_barrier(0);

  // Prologue: A(0),B(0)->buf0 ; A(1)h0->buf1 ; wait the 8 oldest; barrier.
  STAGE_AH(0, 0, 0) STAGE_AH(0, 1, 0)
  STAGE_BH(0, 0, 0) STAGE_BH(0, 1, 0)
  STAGE_AH(1, 0, 1)
  asm volatile("s_waitcnt vmcnt(2)" ::: "memory");
  __builtin_amdgcn_s_barrier();

  #pragma unroll 2
  for (int t = 0; t < NKT; ++t){
    const int p = t & 1;
    // ph0 (mh=0, nh=0)
    LD_AV(p, 0) LD_BV(p, 0)
    if (t + 1 < NKT) STAGE_AH(1 - p, 1, t + 1)
    PH_MFMA(0, 0)
    __builtin_amdgcn_s_barrier();
    // ph1 (0,1)
    LD_BV(p, 1)
    if (t + 1 < NKT) STAGE_BH(1 - p, 0, t + 1)
    PH_MFMA(0, 1)
    __builtin_amdgcn_s_barrier();
    // ph2 (1,0)
    LD_AV(p, 1) LD_BV(p, 0)
    if (t + 1 < NKT) STAGE_BH(1 - p, 1, t + 1)
    PH_MFMA(1, 0)
    __builtin_amdgcn_s_barrier();
    // ph3 (1,1)
    LD_BV(p, 1)
    if (t + 2 < NKT) STAGE_AH(p, 0, t + 2)
    PH_MFMA(1, 1)
    if (t + 2 < NKT)      { asm volatile("s_waitcnt vmcnt(2)" ::: "memory"); }
    else if (t + 1 < NKT) { asm volatile("s_waitcnt vmcnt(0)" ::: "memory"); }
    __builtin_amdgcn_s_barrier();
  }

  // ---- fused epilogue: d2 -> dist -> exp -> *W, then column-sum ----
  const int rowbase0 = bm * BM + wr * 128;
  f32x4 rs[8];
  #pragma unroll
  for (int mi = 0; mi < 8; ++mi) rs[mi] = (f32x4){0.f, 0.f, 0.f, 0.f};

  f32x4 x2r[8];
  #pragma unroll
  for (int mi = 0; mi < 8; ++mi)
    x2r[mi] = *(const f32x4*)&x2[rowbase0 + mi * 16 + lhi * 4];

  #pragma unroll
  for (int ni = 0; ni < 4; ++ni){
    const int col = bn * BN + wc * 64 + ni * 16 + l15;
    const float c2v = c2[col], bt = beta[col], wv = W[col];
    #pragma unroll
    for (int mi = 0; mi < 8; ++mi)
      #pragma unroll
      for (int j = 0; j < 4; ++j){
        float s    = acc[mi][ni][j];
        float d2   = x2r[mi][j] + c2v - 2.0f * s;
        float dist = sqrtf(fmaxf(d2, 0.0f));
        rs[mi][j] += wv * __expf(-bt * dist);   // exp(<=0) can't be inf
      }
  }

  // reduce over the 16 lanes holding different cols; write per-(bn,wc) partials
  const size_t pcbase = (size_t)(bn * 4 + wc) * Bsz;
  #pragma unroll
  for (int mi = 0; mi < 8; ++mi){
    #pragma unroll
    for (int j = 0; j < 4; ++j){
      float v = rs[mi][j];
      v += __shfl_xor(v, 1, 16);
      v += __shfl_xor(v, 2, 16);
      v += __shfl_xor(v, 4, 16);
      v += __shfl_xor(v, 8, 16);
      rs[mi][j] = v;
    }
    if (l15 == 0)
      *(f32x4*)&partials[pcbase + rowbase0 + mi * 16 + lhi * 4] = rs[mi];
  }
}

// ---------------- final reduction over column-groups ----------------
__global__ __launch_bounds__(256) void reduce_kernel(
    const float* __restrict__ partials, const float* __restrict__ bias,
    float* __restrict__ out)
{
  int b = blockIdx.x * 256 + threadIdx.x;
  float s = bias[0];
  #pragma unroll
  for (int t = 0; t < NPC; ++t) s += partials[(size_t)t * Bsz + b];
  out[b] = s;
}

// ---------------- naive f32 fallback (only if ws too small) ----------------
__global__ __launch_bounds__(256) void rbf_naive_kernel(
    const float* __restrict__ x, const float* __restrict__ cen,
    const float* __restrict__ beta, const float* __restrict__ W,
    const float* __restrict__ bias, float* __restrict__ out)
{
  __shared__ float4 xs4[Dsz / 4];
  __shared__ float red[256];
  int b = blockIdx.x;
  for (int i = threadIdx.x; i < Dsz / 4; i += 256)
    xs4[i] = ((const float4*)(x + (size_t)b * Dsz))[i];
  __syncthreads();
  float acc = 0.f;
  for (int j = threadIdx.x; j < Csz; j += 256){
    const float4* c4 = (const float4*)(cen + (size_t)j * Dsz);
    float d2 = 0.f;
    for (int k = 0; k < Dsz / 4; ++k){
      float4 cv = c4[k], xv = xs4[k];
      float a0 = xv.x - cv.x, a1 = xv.y - cv.y, a2 = xv.z - cv.z, a3 = xv.w - cv.w;
      d2 += a0*a0 + a1*a1 + a2*a2 + a3*a3;
    }
    acc += W[j] * expf(-beta[j] * sqrtf(fmaxf(d2, 0.f)));
  }
  red[threadIdx.x] = acc;
  __syncthreads();
  for (int s = 128; s >= 1; s >>= 1){
    if (threadIdx.x < s) red[threadIdx.x] += red[threadIdx.x + s];
    __syncthreads();
  }
  if (threadIdx.x == 0) out[b] = red[0] + bias[0];
}

extern "C" void kernel_launch(void* const* d_in, const int* in_sizes, int n_in,
                              void* d_out, int out_size, void* d_ws, size_t ws_size,
                              hipStream_t stream)
{
  const float* x    = (const float*)d_in[0];
  const float* cen  = (const float*)d_in[1];
  const float* beta = (const float*)d_in[2];
  const float* W    = (const float*)d_in[3];
  const float* bias = (const float*)d_in[4];
  float* out = (float*)d_out;

  const size_t off_xb = 0;
  const size_t off_cb = off_xb + (size_t)Bsz * Dsz * sizeof(unsigned short);
  const size_t off_x2 = off_cb + (size_t)Csz * Dsz * sizeof(unsigned short);
  const size_t off_c2 = off_x2 + (size_t)Bsz * sizeof(float);
  const size_t off_p  = off_c2 + (size_t)Csz * sizeof(float);
  const size_t need   = off_p  + (size_t)NPC * Bsz * sizeof(float);

  if (ws_size < need){
    rbf_naive_kernel<<<Bsz, 256, 0, stream>>>(x, cen, beta, W, bias, out);
    return;
  }

  char* ws = (char*)d_ws;
  unsigned short* xb = (unsigned short*)(ws + off_xb);
  unsigned short* cb = (unsigned short*)(ws + off_cb);
  float* x2 = (float*)(ws + off_x2);
  float* c2 = (float*)(ws + off_c2);
  float* pp = (float*)(ws + off_p);

  prep_kernel<<<(Bsz + Csz) / 4, 256, 0, stream>>>(x, cen, xb, cb, x2, c2);
  dim3 grid(Bsz / BM, Csz / BN);
  rbf_gemm_kernel<<<grid, 512, 0, stream>>>(xb, cb, x2, c2, beta, W, pp);
  reduce_kernel<<<Bsz / 256, 256, 0, stream>>>(pp, bias, out);
}

// Round 4
// 71.358 us; speedup vs baseline: 1.0351x; 1.0318x over previous
//
#include <hip/hip_runtime.h>

typedef __bf16 bf16_t;
typedef bf16_t bf16x8 __attribute__((ext_vector_type(8)));
typedef float f32x4 __attribute__((ext_vector_type(4)));

#define Bsz 4096   // batch rows (M)
#define Csz 4096   // centers (N)
#define Dsz 1024   // data dim (K)
#define BM 256
#define BN 256
#define BK 64
#define NKT (Dsz/BK)        // 16 K-tiles
#define NPC 64              // partial column-groups: 16 n-tiles x 4 wc

// RNE f32 -> bf16 bits
__device__ inline unsigned short f2bf(float f){
  unsigned u = __float_as_uint(f);
  u += 0x7FFFu + ((u >> 16) & 1u);
  return (unsigned short)(u >> 16);
}

// inline-asm LDS read: opaque to alias analysis, so the compiler cannot
// insert vmcnt(0) drains against the global_load_lds prefetch queue.
__device__ __forceinline__ bf16x8 dsr128(unsigned byte_off){
  bf16x8 r;
  asm volatile("ds_read_b128 %0, %1" : "=v"(r) : "v"(byte_off));
  return r;
}

// ---------------- prep: x2/c2 (f32 exact) + bf16 conversion ----------------
__global__ __launch_bounds__(256) void prep_kernel(
    const float* __restrict__ x, const float* __restrict__ cen,
    unsigned short* __restrict__ xb, unsigned short* __restrict__ cb,
    float* __restrict__ x2, float* __restrict__ c2)
{
  int w = blockIdx.x * 4 + (threadIdx.x >> 6);   // global wave id, one row each
  int lane = threadIdx.x & 63;
  const float* src; unsigned short* dst; float* sq; int row;
  if (w < Bsz) { row = w;       src = x;   dst = xb; sq = x2; }
  else         { row = w - Bsz; src = cen; dst = cb; sq = c2; }

  const float4* s4 = (const float4*)(src + (size_t)row * Dsz);
  unsigned short* d = dst + (size_t)row * Dsz;
  float ss = 0.f;
  #pragma unroll
  for (int t = 0; t < 4; ++t){
    float4 v = s4[t * 64 + lane];
    ss += v.x*v.x + v.y*v.y + v.z*v.z + v.w*v.w;
    ushort4 u; u.x = f2bf(v.x); u.y = f2bf(v.y); u.z = f2bf(v.z); u.w = f2bf(v.w);
    *(ushort4*)(d + (size_t)(t * 64 + lane) * 4) = u;
  }
  #pragma unroll
  for (int off = 32; off >= 1; off >>= 1) ss += __shfl_xor(ss, off, 64);
  if (lane == 0) sq[row] = ss;
}

// ------------- 256x256 free-flow fused GEMM + RBF epilogue -------------
// 512 thr = 8 waves (2 wr x 4 wc). Per wave: 128x64 output = 8x4 frags 16x16.
// LDS: 2 bufs x (A 256x64 + B 256x64) bf16 = 128 KiB, XOR chunk-swizzled:
//   LDS[r][c16] = G[r][c16 ^ (r&7)]  (linear gload_lds dest, pre-swz source).
// Per K-tile, ONE barrier (at tile end). Within the tile waves free-flow:
//   issue B+A0 ds_reads -> stage FULL next tile (8 gload_lds, age ~= 1 tile)
//   -> lgkm0 -> 32 MFMA -> issue A1 reads -> lgkm0 -> 32 MFMA
//   -> vmcnt(0) (free: stages are a full tile old) -> barrier.
// Correctness: reads hit buf p (finalized at previous tile-end barrier);
// stages hit buf 1-p whose readers all finished before that same barrier.
__global__ __launch_bounds__(512, 2) void rbf_gemm_kernel(
    const unsigned short* __restrict__ xb, const unsigned short* __restrict__ cb,
    const float* __restrict__ x2, const float* __restrict__ c2,
    const float* __restrict__ beta, const float* __restrict__ W,
    float* __restrict__ partials)
{
  __shared__ __align__(16) unsigned short smem[65536];  // 128 KiB

  const int tid  = threadIdx.x;
  const int wid  = tid >> 6;
  const int lane = tid & 63;
  const int wr   = wid >> 2;        // 0..1
  const int wc   = wid & 3;         // 0..3
  const int l15  = lane & 15;
  const int lhi  = lane >> 4;

  // XCD-rect mapping: xcd = id%8 (round-robin heuristic); each XCD owns two
  // 4x4 (bm,bn) rectangles -> per-XCD L2 working set 6 MB (vs ~9 MB scattered).
  const int id   = blockIdx.x;
  const int xcd  = id & 7;
  const int jj   = id >> 3;                 // 0..31
  const int rect = xcd + 8 * (jj >> 4);     // 0..15
  const int pos  = jj & 15;                 // 0..15
  const int bm   = (rect & 3) * 4 + (pos & 3);
  const int bn   = (rect >> 2) * 4 + (pos >> 2);

  const unsigned short* gA = xb + (size_t)(bm * BM) * Dsz;
  const unsigned short* gB = cb + (size_t)(bn * BN) * Dsz;

  // staging geometry: one gload_lds = 64 lanes x 16B; 512 thr cover 64 rows
  const int srow   = tid >> 3;                 // 0..63
  const int schunk = (tid & 7) ^ (srow & 7);   // pre-swizzled src 16B chunk

  // read-side swizzled chunk offsets (ushort units), kk = 0/1
  const int ach0 = ((lhi)     ^ (l15 & 7)) * 8;
  const int ach1 = ((4 + lhi) ^ (l15 & 7)) * 8;
  const int ldsA = wr * 8192;                  // A-half(wr) base (ushorts)
  const int ldsB = 16384 + (wc >> 1) * 8192;   // B-half(wc>>1) base
  const int bloc = (wc & 1) * 64;              // row offset within B-half

  // 32-bit LDS byte offsets for inline-asm ds_read
  const unsigned lds_base =
      (unsigned)(uintptr_t)(__attribute__((address_space(3))) unsigned short*)smem;
  const unsigned aoff0 = lds_base + (unsigned)(ldsA + l15 * 64 + ach0) * 2u;
  const unsigned aoff1 = lds_base + (unsigned)(ldsA + l15 * 64 + ach1) * 2u;
  const unsigned boff0 = lds_base + (unsigned)(ldsB + (bloc + l15) * 64 + ach0) * 2u;
  const unsigned boff1 = lds_base + (unsigned)(ldsB + (bloc + l15) * 64 + ach1) * 2u;

#define STAGE_H(GP, LBASE, GROW0, KT) { \
    const unsigned short* gsrc_ = (GP) + (size_t)((GROW0) + srow) * Dsz + (KT)*BK + schunk*8; \
    __builtin_amdgcn_global_load_lds( \
      (const __attribute__((address_space(1))) unsigned int*)gsrc_, \
      (__attribute__((address_space(3))) unsigned int*)&smem[(LBASE) + wid*512], 16, 0, 0); \
    __builtin_amdgcn_global_load_lds( \
      (const __attribute__((address_space(1))) unsigned int*)(gsrc_ + (size_t)64 * Dsz), \
      (__attribute__((address_space(3))) unsigned int*)&smem[(LBASE) + 4096 + wid*512], 16, 0, 0); }

  // stage the FULL tile KT into buf P (8 gload_lds per thread)
#define STAGE_T(P, KT) { \
    STAGE_H(gA, (P)*32768 +     0,   0, KT) \
    STAGE_H(gA, (P)*32768 +  8192, 128, KT) \
    STAGE_H(gB, (P)*32768 + 16384,   0, KT) \
    STAGE_H(gB, (P)*32768 + 24576, 128, KT) }

  f32x4 acc[8][4];
  #pragma unroll
  for (int mi = 0; mi < 8; ++mi)
    #pragma unroll
    for (int ni = 0; ni < 4; ++ni)
      acc[mi][ni] = (f32x4){0.f, 0.f, 0.f, 0.f};

  bf16x8 av[4][2], bv[4][2];

#define LD_B(P) { \
    _Pragma("unroll") \
    for (int ni_ = 0; ni_ < 4; ++ni_){ \
      bv[ni_][0] = dsr128(boff0 + (P)*65536u + ni_*2048u); \
      bv[ni_][1] = dsr128(boff1 + (P)*65536u + ni_*2048u); \
    } }

#define LD_A(P, MH) { \
    _Pragma("unroll") \
    for (int mi_ = 0; mi_ < 4; ++mi_){ \
      av[mi_][0] = dsr128(aoff0 + (P)*65536u + (MH)*8192u + mi_*2048u); \
      av[mi_][1] = dsr128(aoff1 + (P)*65536u + (MH)*8192u + mi_*2048u); \
    } }

#define MFMA_H(MH) { \
    _Pragma("unroll") \
    for (int mi_ = 0; mi_ < 4; ++mi_) \
      _Pragma("unroll") \
      for (int ni_ = 0; ni_ < 4; ++ni_){ \
        acc[(MH)*4+mi_][ni_] = __builtin_amdgcn_mfma_f32_16x16x32_bf16(av[mi_][0], bv[ni_][0], acc[(MH)*4+mi_][ni_], 0,0,0); \
        acc[(MH)*4+mi_][ni_] = __builtin_amdgcn_mfma_f32_16x16x32_bf16(av[mi_][1], bv[ni_][1], acc[(MH)*4+mi_][ni_], 0,0,0); \
      } }

  // Prologue: stage tile 0 into buf0, drain, sync.
  STAGE_T(0, 0)
  asm volatile("s_waitcnt vmcnt(0)" ::: "memory");
  __builtin_amdgcn_s_barrier();

  #pragma unroll 2
  for (int t = 0; t < NKT; ++t){
    const int p = t & 1;
    LD_B(p)
    LD_A(p, 0)
    if (t + 1 < NKT) STAGE_T(1 - p, t + 1)
    asm volatile("s_waitcnt lgkmcnt(0)" ::: "memory");
    __builtin_amdgcn_sched_barrier(0);
    __builtin_amdgcn_s_setprio(1);
    MFMA_H(0)
    __builtin_amdgcn_s_setprio(0);
    __builtin_amdgcn_sched_barrier(0);
    LD_A(p, 1)
    asm volatile("s_waitcnt lgkmcnt(0)" ::: "memory");
    __builtin_amdgcn_sched_barrier(0);
    __builtin_amdgcn_s_setprio(1);
    MFMA_H(1)
    __builtin_amdgcn_s_setprio(0);
    __builtin_amdgcn_sched_barrier(0);
    asm volatile("s_waitcnt vmcnt(0)" ::: "memory");   // stages are ~1 tile old
    __builtin_amdgcn_sched_barrier(0);
    __builtin_amdgcn_s_barrier();                      // the ONLY barrier/tile
  }

  // ---- fused epilogue: d2 -> dist -> exp -> *W, then column-sum ----
  const int rowbase0 = bm * BM + wr * 128;
  f32x4 rs[8];
  #pragma unroll
  for (int mi = 0; mi < 8; ++mi) rs[mi] = (f32x4){0.f, 0.f, 0.f, 0.f};

  f32x4 x2r[8];
  #pragma unroll
  for (int mi = 0; mi < 8; ++mi)
    x2r[mi] = *(const f32x4*)&x2[rowbase0 + mi * 16 + lhi * 4];

  #pragma unroll
  for (int ni = 0; ni < 4; ++ni){
    const int col = bn * BN + wc * 64 + ni * 16 + l15;
    const float c2v = c2[col], bt = beta[col], wv = W[col];
    #pragma unroll
    for (int mi = 0; mi < 8; ++mi)
      #pragma unroll
      for (int j = 0; j < 4; ++j){
        float s    = acc[mi][ni][j];
        float d2   = x2r[mi][j] + c2v - 2.0f * s;
        float dist = sqrtf(fmaxf(d2, 0.0f));
        rs[mi][j] += wv * __expf(-bt * dist);   // exp(<=0) can't be inf
      }
  }

  // reduce over the 16 lanes holding different cols; write per-(bn,wc) partials
  const size_t pcbase = (size_t)(bn * 4 + wc) * Bsz;
  #pragma unroll
  for (int mi = 0; mi < 8; ++mi){
    #pragma unroll
    for (int j = 0; j < 4; ++j){
      float v = rs[mi][j];
      v += __shfl_xor(v, 1, 16);
      v += __shfl_xor(v, 2, 16);
      v += __shfl_xor(v, 4, 16);
      v += __shfl_xor(v, 8, 16);
      rs[mi][j] = v;
    }
    if (l15 == 0)
      *(f32x4*)&partials[pcbase + rowbase0 + mi * 16 + lhi * 4] = rs[mi];
  }
}

// ---------------- final reduction over column-groups ----------------
__global__ __launch_bounds__(256) void reduce_kernel(
    const float* __restrict__ partials, const float* __restrict__ bias,
    float* __restrict__ out)
{
  int b = blockIdx.x * 256 + threadIdx.x;
  float s = bias[0];
  #pragma unroll
  for (int t = 0; t < NPC; ++t) s += partials[(size_t)t * Bsz + b];
  out[b] = s;
}

// ---------------- naive f32 fallback (only if ws too small) ----------------
__global__ __launch_bounds__(256) void rbf_naive_kernel(
    const float* __restrict__ x, const float* __restrict__ cen,
    const float* __restrict__ beta, const float* __restrict__ W,
    const float* __restrict__ bias, float* __restrict__ out)
{
  __shared__ float4 xs4[Dsz / 4];
  __shared__ float red[256];
  int b = blockIdx.x;
  for (int i = threadIdx.x; i < Dsz / 4; i += 256)
    xs4[i] = ((const float4*)(x + (size_t)b * Dsz))[i];
  __syncthreads();
  float acc = 0.f;
  for (int j = threadIdx.x; j < Csz; j += 256){
    const float4* c4 = (const float4*)(cen + (size_t)j * Dsz);
    float d2 = 0.f;
    for (int k = 0; k < Dsz / 4; ++k){
      float4 cv = c4[k], xv = xs4[k];
      float a0 = xv.x - cv.x, a1 = xv.y - cv.y, a2 = xv.z - cv.z, a3 = xv.w - cv.w;
      d2 += a0*a0 + a1*a1 + a2*a2 + a3*a3;
    }
    acc += W[j] * expf(-beta[j] * sqrtf(fmaxf(d2, 0.f)));
  }
  red[threadIdx.x] = acc;
  __syncthreads();
  for (int s = 128; s >= 1; s >>= 1){
    if (threadIdx.x < s) red[threadIdx.x] += red[threadIdx.x + s];
    __syncthreads();
  }
  if (threadIdx.x == 0) out[b] = red[0] + bias[0];
}

extern "C" void kernel_launch(void* const* d_in, const int* in_sizes, int n_in,
                              void* d_out, int out_size, void* d_ws, size_t ws_size,
                              hipStream_t stream)
{
  const float* x    = (const float*)d_in[0];
  const float* cen  = (const float*)d_in[1];
  const float* beta = (const float*)d_in[2];
  const float* W    = (const float*)d_in[3];
  const float* bias = (const float*)d_in[4];
  float* out = (float*)d_out;

  const size_t off_xb = 0;
  const size_t off_cb = off_xb + (size_t)Bsz * Dsz * sizeof(unsigned short);
  const size_t off_x2 = off_cb + (size_t)Csz * Dsz * sizeof(unsigned short);
  const size_t off_c2 = off_x2 + (size_t)Bsz * sizeof(float);
  const size_t off_p  = off_c2 + (size_t)Csz * sizeof(float);
  const size_t need   = off_p  + (size_t)NPC * Bsz * sizeof(float);

  if (ws_size < need){
    rbf_naive_kernel<<<Bsz, 256, 0, stream>>>(x, cen, beta, W, bias, out);
    return;
  }

  char* ws = (char*)d_ws;
  unsigned short* xb = (unsigned short*)(ws + off_xb);
  unsigned short* cb = (unsigned short*)(ws + off_cb);
  float* x2 = (float*)(ws + off_x2);
  float* c2 = (float*)(ws + off_c2);
  float* pp = (float*)(ws + off_p);

  prep_kernel<<<(Bsz + Csz) / 4, 256, 0, stream>>>(x, cen, xb, cb, x2, c2);
  rbf_gemm_kernel<<<256, 512, 0, stream>>>(xb, cb, x2, c2, beta, W, pp);
  reduce_kernel<<<Bsz / 256, 256, 0, stream>>>(pp, bias, out);
}